// Round 1
// baseline (691.381 us; speedup 1.0000x reference)
//
#include <hip/hip_runtime.h>
#include <hip/hip_bf16.h>

typedef float f32x4 __attribute__((ext_vector_type(4)));
typedef __bf16 bf16x8 __attribute__((ext_vector_type(8)));

#define WSTR 80            // padded LDS stride (bf16 elems): 160B, keeps 16B align, breaks worst bank conflicts
#define INV_SQRT3 0.57735026918962576f

// out_s[n,w]   = sum_u s1*s2*Wss[u,w] + sum_u (v1[n,u,:].v2)*inv_sqrt3*Wvv[u,w] + bias[w]
// out_v[n,w,i] = (s1@Wsv)[n,w]*v2[n,i] + (v1_i@Wvs)[n,w]*s2[n]
// (all other reference scale factors cancel exactly)
__global__ __launch_bounds__(256, 2) void o3tp_kernel(
    const float* __restrict__ in1, const float* __restrict__ in2,
    const float* __restrict__ Wss, const float* __restrict__ Wvv,
    const float* __restrict__ Wsv, const float* __restrict__ Wvs,
    const float* __restrict__ bias, float* __restrict__ out, int n)
{
    __shared__ __align__(16) __bf16 ldsW[4 * 64 * WSTR];   // 40 KB: W^T per matrix, [w][u]

    const int tid  = threadIdx.x;
    const int lane = tid & 63;
    const int wvid = tid >> 6;       // wave id 0..3
    const int m16  = lane & 15;      // MFMA row-in-tile (A) / col w (B,C)
    const int kblk = lane >> 4;      // MFMA k-block (A,B) / row-quad (C)

    // ---- stage weights -> LDS transposed bf16 (once per block) ----
    const float* Ws[4] = {Wss, Wvv, Wsv, Wvs};
    #pragma unroll
    for (int m = 0; m < 4; ++m) {
        const float* W = Ws[m];
        __bf16* dst = ldsW + m * (64 * WSTR);
        #pragma unroll
        for (int i = 0; i < 4; ++i) {
            int e = i * 1024 + tid * 4;         // element idx in row-major W[u][w]
            f32x4 wv4 = *(const f32x4*)(W + e);
            int u = e >> 6;
            int w = e & 63;
            dst[(w+0)*WSTR + u] = (__bf16)wv4.x;
            dst[(w+1)*WSTR + u] = (__bf16)wv4.y;
            dst[(w+2)*WSTR + u] = (__bf16)wv4.z;
            dst[(w+3)*WSTR + u] = (__bf16)wv4.w;
        }
    }

    // ---- per-lane A fragments, straight from global (each input elem read exactly once) ----
    const long row0 = (long)blockIdx.x * 64 + wvid * 16;
    long rowA = row0 + m16;
    if (rowA >= n) rowA = n - 1;

    f32x4 e2 = *(const f32x4*)(in2 + rowA * 4);          // s2, v2x, v2y, v2z
    const float s2 = e2.x;

    bf16x8 a_s1[2], a_xss[2], a_xvv[2], a_v0[2], a_v1[2], a_v2[2];
    #pragma unroll
    for (int ks = 0; ks < 2; ++ks) {
        const int ubase = ks * 32 + kblk * 8;
        const float* ps = in1 + rowA * 256 + ubase;
        f32x4 sa = *(const f32x4*)(ps);
        f32x4 sb = *(const f32x4*)(ps + 4);
        float s1v[8] = {sa.x, sa.y, sa.z, sa.w, sb.x, sb.y, sb.z, sb.w};

        const float* pv = in1 + rowA * 256 + 64 + 3 * ubase;   // 24 consecutive floats, 16B aligned
        f32x4 va = *(const f32x4*)(pv);
        f32x4 vb = *(const f32x4*)(pv + 4);
        f32x4 vc = *(const f32x4*)(pv + 8);
        f32x4 vd = *(const f32x4*)(pv + 12);
        f32x4 ve = *(const f32x4*)(pv + 16);
        f32x4 vf = *(const f32x4*)(pv + 20);
        float vvv[24] = {va.x,va.y,va.z,va.w, vb.x,vb.y,vb.z,vb.w,
                         vc.x,vc.y,vc.z,vc.w, vd.x,vd.y,vd.z,vd.w,
                         ve.x,ve.y,ve.z,ve.w, vf.x,vf.y,vf.z,vf.w};
        #pragma unroll
        for (int j = 0; j < 8; ++j) {
            float s1j = s1v[j];
            a_s1 [ks][j] = (__bf16)s1j;
            a_xss[ks][j] = (__bf16)(s1j * s2);
            float x = vvv[3*j+0], y = vvv[3*j+1], z = vvv[3*j+2];
            a_v0[ks][j] = (__bf16)x;
            a_v1[ks][j] = (__bf16)y;
            a_v2[ks][j] = (__bf16)z;
            a_xvv[ks][j] = (__bf16)((x*e2.y + y*e2.z + z*e2.w) * INV_SQRT3);
        }
    }

    // ---- per-lane epilogue row scalars (C rows = row0 + kblk*4 + r) ----
    const long rowsE = row0 + kblk * 4;
    f32x4 q2[4];
    #pragma unroll
    for (int r = 0; r < 4; ++r) {
        long rr = rowsE + r; if (rr >= n) rr = n - 1;
        q2[r] = *(const f32x4*)(in2 + rr * 4);
    }

    __syncthreads();   // weights staged

    // ---- 4 col-tiles of 16 outputs each ----
    #pragma unroll
    for (int nt = 0; nt < 4; ++nt) {
        const int w = nt * 16 + m16;
        const int bo = w * WSTR + kblk * 8;
        const __bf16* pss = ldsW + 0*(64*WSTR) + bo;
        const __bf16* pvv = ldsW + 1*(64*WSTR) + bo;
        const __bf16* psv = ldsW + 2*(64*WSTR) + bo;
        const __bf16* pvs = ldsW + 3*(64*WSTR) + bo;
        bf16x8 b_ss0 = *(const bf16x8*)(pss);
        bf16x8 b_ss1 = *(const bf16x8*)(pss + 32);
        bf16x8 b_vv0 = *(const bf16x8*)(pvv);
        bf16x8 b_vv1 = *(const bf16x8*)(pvv + 32);
        bf16x8 b_sv0 = *(const bf16x8*)(psv);
        bf16x8 b_sv1 = *(const bf16x8*)(psv + 32);
        bf16x8 b_vs0 = *(const bf16x8*)(pvs);
        bf16x8 b_vs1 = *(const bf16x8*)(pvs + 32);

        f32x4 acc_s  = {0.f,0.f,0.f,0.f};
        f32x4 acc_sv = {0.f,0.f,0.f,0.f};
        f32x4 acc_w0 = {0.f,0.f,0.f,0.f};
        f32x4 acc_w1 = {0.f,0.f,0.f,0.f};
        f32x4 acc_w2 = {0.f,0.f,0.f,0.f};

        acc_s  = __builtin_amdgcn_mfma_f32_16x16x32_bf16(a_xss[0], b_ss0, acc_s, 0,0,0);
        acc_s  = __builtin_amdgcn_mfma_f32_16x16x32_bf16(a_xss[1], b_ss1, acc_s, 0,0,0);
        acc_s  = __builtin_amdgcn_mfma_f32_16x16x32_bf16(a_xvv[0], b_vv0, acc_s, 0,0,0);
        acc_s  = __builtin_amdgcn_mfma_f32_16x16x32_bf16(a_xvv[1], b_vv1, acc_s, 0,0,0);
        acc_sv = __builtin_amdgcn_mfma_f32_16x16x32_bf16(a_s1[0],  b_sv0, acc_sv, 0,0,0);
        acc_sv = __builtin_amdgcn_mfma_f32_16x16x32_bf16(a_s1[1],  b_sv1, acc_sv, 0,0,0);
        acc_w0 = __builtin_amdgcn_mfma_f32_16x16x32_bf16(a_v0[0],  b_vs0, acc_w0, 0,0,0);
        acc_w0 = __builtin_amdgcn_mfma_f32_16x16x32_bf16(a_v0[1],  b_vs1, acc_w0, 0,0,0);
        acc_w1 = __builtin_amdgcn_mfma_f32_16x16x32_bf16(a_v1[0],  b_vs0, acc_w1, 0,0,0);
        acc_w1 = __builtin_amdgcn_mfma_f32_16x16x32_bf16(a_v1[1],  b_vs1, acc_w1, 0,0,0);
        acc_w2 = __builtin_amdgcn_mfma_f32_16x16x32_bf16(a_v2[0],  b_vs0, acc_w2, 0,0,0);
        acc_w2 = __builtin_amdgcn_mfma_f32_16x16x32_bf16(a_v2[1],  b_vs1, acc_w2, 0,0,0);

        const float bw = bias[w];
        #pragma unroll
        for (int r = 0; r < 4; ++r) {
            long rr = rowsE + r;
            if (rr < n) {
                float* op = out + rr * 256;
                op[w] = acc_s[r] + bw;
                float sve = acc_sv[r], s2e = q2[r].x;
                op[64 + 3*w + 0] = sve * q2[r].y + acc_w0[r] * s2e;
                op[64 + 3*w + 1] = sve * q2[r].z + acc_w1[r] * s2e;
                op[64 + 3*w + 2] = sve * q2[r].w + acc_w2[r] * s2e;
            }
        }
    }
}

extern "C" void kernel_launch(void* const* d_in, const int* in_sizes, int n_in,
                              void* d_out, int out_size, void* d_ws, size_t ws_size,
                              hipStream_t stream) {
    const float* in1  = (const float*)d_in[0];
    const float* in2  = (const float*)d_in[1];
    const float* Wss  = (const float*)d_in[2];
    const float* Wvv  = (const float*)d_in[3];
    const float* Wsv  = (const float*)d_in[4];
    const float* Wvs  = (const float*)d_in[5];
    const float* bias = (const float*)d_in[6];
    float* out = (float*)d_out;
    const int n = in_sizes[0] / 256;
    const int blocks = (n + 63) / 64;
    o3tp_kernel<<<blocks, 256, 0, stream>>>(in1, in2, Wss, Wvv, Wsv, Wvs, bias, out, n);
}